// Round 2
// baseline (1295.341 us; speedup 1.0000x reference)
//
#include <hip/hip_runtime.h>

#define HW 16384
#define CCH 256
#define BB 16

typedef __fp16 half2v __attribute__((ext_vector_type(2)));

#if defined(__has_builtin)
#if __has_builtin(__builtin_amdgcn_fdot2)
#define HAVE_FDOT2 1
#endif
#endif

__device__ __forceinline__ float dot2acc(half2v a, half2v b, float c) {
#ifdef HAVE_FDOT2
  return __builtin_amdgcn_fdot2(a, b, c, false);
#else
  return c + (float)a[0] * (float)b[0] + (float)a[1] * (float)b[1];
#endif
}

// ---------------- K1: predictor partial sums ----------------
// grid (64, 16), block 256. One pixel per thread.
__global__ __launch_bounds__(256) void pred_kernel(
    const float* __restrict__ x, const float* __restrict__ w1,
    const float* __restrict__ b1, const float* __restrict__ w2,
    const float* __restrict__ b2, float* __restrict__ sums) {
  const int b = blockIdx.y;
  const int pix = blockIdx.x * 256 + threadIdx.x;
  const float* xb = x + ((size_t)b * CCH) * HW + pix;

  float acc[32];
#pragma unroll
  for (int o = 0; o < 32; ++o) acc[o] = 0.f;

  for (int c = 0; c < CCH; ++c) {
    float xv = xb[(size_t)c * HW];           // coalesced across lanes
#pragma unroll
    for (int o = 0; o < 32; ++o)             // w1 index wave-uniform -> s_load
      acc[o] = fmaf(w1[o * CCH + c], xv, acc[o]);
  }

  float z = b2[0];
#pragma unroll
  for (int o = 0; o < 32; ++o) {
    float h = fmaxf(acc[o] + b1[o], 0.f);
    z = fmaf(h, w2[o], z);
  }
  float pred = fmaxf(z, 0.f) * 20.f + 1.f;

  // wave reduce (64 lanes) then block reduce
#pragma unroll
  for (int off = 32; off > 0; off >>= 1) pred += __shfl_down(pred, off);
  __shared__ float wsum[4];
  if ((threadIdx.x & 63) == 0) wsum[threadIdx.x >> 6] = pred;
  __syncthreads();
  if (threadIdx.x == 0) {
    float t = wsum[0] + wsum[1] + wsum[2] + wsum[3];
    atomicAdd(&sums[b], t);
  }
}

// ---------------- K2: finalize radii ----------------
__global__ void finalize_kernel(const float* __restrict__ sums,
                                int* __restrict__ rads) {
  int t = threadIdx.x;
  if (t < BB) {
    float mean = sums[t] * (1.f / (float)HW);
    float ksz = floorf(mean);
    ksz = fminf(fmaxf(ksz, 1.f), 21.f);
    int rad = (int)floorf((ksz - 1.f) * 0.5f);
    rads[t] = rad;
  }
}

// ---------------- K3: depthwise adaptive conv ----------------
// grid (4, 256, 16), block 128. 64x64 output tile, 84x84 halo in LDS.
// Each thread computes an 8-wide x 4-tall output patch.
__global__ __launch_bounds__(128) void conv_kernel(
    const float* __restrict__ x, const float* __restrict__ gauss,
    const int* __restrict__ rads, float* __restrict__ out) {
  __shared__ float tile[84 * 88];

  const int b = blockIdx.z, c = blockIdx.y;
  const int x0 = (blockIdx.x & 1) * 64, y0 = (blockIdx.x >> 1) * 64;
  const int r = rads[b];  // wave-uniform
  const int tid = threadIdx.x;
  const float* img = x + ((size_t)(b * CCH + c)) * HW;

  // load halo tile with reflect padding (JAX 'reflect': -i -> i, 127+i -> 127-i)
  for (int i = tid; i < 84 * 84; i += 128) {
    int yy = i / 84, xx = i - yy * 84;
    int gy = y0 + yy - 10;
    gy = gy < 0 ? -gy : (gy > 127 ? 254 - gy : gy);
    int gx = x0 + xx - 10;
    gx = gx < 0 ? -gx : (gx > 127 ? 254 - gx : gx);
    tile[yy * 88 + xx] = img[gy * 128 + gx];
  }
  __syncthreads();

  const int tx = tid & 7, ty = tid >> 3;  // 8 x 16 threads
  const int xs = tx * 8, ys = ty * 4;
  const float* g = gauss + (size_t)c * 441;

  float acc[4][8];
#pragma unroll
  for (int o = 0; o < 4; ++o)
#pragma unroll
    for (int j = 0; j < 8; ++j) acc[o][j] = 0.f;

  for (int k = 0; k < 24; ++k) {
    if (k < 10 - r || k > 13 + r) continue;  // uniform: row contributes nothing

    // register window: LDS row (ys+k), cols xs..xs+27 (aligned float4 reads)
    float win[29];
    const float* row = &tile[(ys + k) * 88 + xs];
#pragma unroll
    for (int t4 = 0; t4 < 7; ++t4) {
      float4 v = *(const float4*)(row + 4 * t4);
      win[4 * t4 + 0] = v.x; win[4 * t4 + 1] = v.y;
      win[4 * t4 + 2] = v.z; win[4 * t4 + 3] = v.w;
    }
    win[28] = 0.f;

    // pack both parities to f16 pairs
    half2v wa[14], wb[14];
#pragma unroll
    for (int p = 0; p < 14; ++p) {
      wa[p] = __builtin_amdgcn_cvt_pkrtz(win[2 * p], win[2 * p + 1]);
      wb[p] = __builtin_amdgcn_cvt_pkrtz(win[2 * p + 1], win[2 * p + 2]);
    }

#pragma unroll
    for (int o = 0; o < 4; ++o) {
      const int dy = k - 10 - o;
      if (dy < -r || dy > r) continue;  // uniform
      const float* grow = g + (dy + 10) * 21 + 10;
      half2v wp[11];
#pragma unroll
      for (int p = 0; p < 11; ++p) {
        int dx0 = 2 * p - 10, dx1 = dx0 + 1;
        float w0  = (dx0 >= -r && dx0 <= r) ? grow[dx0] : 0.f;  // predicated: no OOB
        float w1v = (dx1 >= -r && dx1 <= r) ? grow[dx1] : 0.f;
        wp[p] = __builtin_amdgcn_cvt_pkrtz(w0, w1v);
      }
#pragma unroll
      for (int j = 0; j < 8; ++j) {
#pragma unroll
        for (int p = 0; p < 11; ++p) {
          // t = j + dx + 10 -> pairs (win[j+2p], win[j+2p+1])
          if (j & 1) acc[o][j] = dot2acc(wp[p], wb[((j - 1) >> 1) + p], acc[o][j]);
          else       acc[o][j] = dot2acc(wp[p], wa[(j >> 1) + p], acc[o][j]);
        }
      }
    }
  }

  float* ob = out + ((size_t)(b * CCH + c)) * HW;
#pragma unroll
  for (int o = 0; o < 4; ++o) {
    int oy = y0 + ys + o, ox = x0 + xs;
    float4 v0 = {acc[o][0], acc[o][1], acc[o][2], acc[o][3]};
    float4 v1 = {acc[o][4], acc[o][5], acc[o][6], acc[o][7]};
    *(float4*)(ob + (size_t)oy * 128 + ox) = v0;
    *(float4*)(ob + (size_t)oy * 128 + ox + 4) = v1;
  }
}

extern "C" void kernel_launch(void* const* d_in, const int* in_sizes, int n_in,
                              void* d_out, int out_size, void* d_ws, size_t ws_size,
                              hipStream_t stream) {
  const float* x     = (const float*)d_in[0];
  const float* gauss = (const float*)d_in[1];
  const float* w1    = (const float*)d_in[2];
  const float* b1    = (const float*)d_in[3];
  const float* w2    = (const float*)d_in[4];
  const float* b2    = (const float*)d_in[5];
  float* out = (float*)d_out;

  float* sums = (float*)d_ws;
  int* rads = (int*)((char*)d_ws + 64);

  (void)hipMemsetAsync(d_ws, 0, 64, stream);  // zero the 16 batch accumulators
  pred_kernel<<<dim3(64, 16), 256, 0, stream>>>(x, w1, b1, w2, b2, sums);
  finalize_kernel<<<1, 64, 0, stream>>>(sums, rads);
  conv_kernel<<<dim3(4, 256, 16), 128, 0, stream>>>(x, gauss, rads, out);
}

// Round 7
// 798.436 us; speedup vs baseline: 1.6223x; 1.6223x over previous
//
#include <hip/hip_runtime.h>

#define HW 16384
#define CCH 256
#define XS_STRIDE 152   // >=148, multiple of 8 (16B-aligned rows), bank step 12 -> full sweep
#define WM_STRIDE 22

typedef _Float16 f16x8 __attribute__((ext_vector_type(8)));
typedef _Float16 f16x4 __attribute__((ext_vector_type(4)));
typedef float f32x4 __attribute__((ext_vector_type(4)));

// ---------------- K1: predictor partial sums ----------------
// grid (64, 16), block 256. One pixel per thread; w1 staged transposed in LDS.
__global__ __launch_bounds__(256) void pred_kernel(
    const float* __restrict__ x, const float* __restrict__ w1,
    const float* __restrict__ b1, const float* __restrict__ w2,
    const float* __restrict__ b2, float* __restrict__ sums) {
  __shared__ float wt[256 * 36];  // [c][o], stride 36 floats (144B, 16B-aligned)
  __shared__ float wsum[4];
  const int tid = threadIdx.x;
  for (int i = tid; i < 8192; i += 256) {
    int o = i >> 8, c = i & 255;     // w1 is [32][256] row-major
    wt[c * 36 + o] = w1[i];
  }
  __syncthreads();

  const int b = blockIdx.y;
  const int pix = blockIdx.x * 256 + tid;
  const float* xb = x + (size_t)b * CCH * HW + pix;

  float ac[32];
#pragma unroll
  for (int o = 0; o < 32; ++o) ac[o] = 0.f;

#pragma unroll 2
  for (int c = 0; c < CCH; ++c) {
    float xv = xb[(size_t)c * HW];   // coalesced 256B/wave
#pragma unroll
    for (int o4 = 0; o4 < 8; ++o4) {
      f32x4 w = *(const f32x4*)&wt[c * 36 + o4 * 4];  // uniform -> LDS broadcast
#pragma unroll
      for (int e = 0; e < 4; ++e) ac[o4 * 4 + e] = fmaf(w[e], xv, ac[o4 * 4 + e]);
    }
  }

  float z = b2[0];
#pragma unroll
  for (int o = 0; o < 32; ++o) z = fmaf(fmaxf(ac[o] + b1[o], 0.f), w2[o], z);
  float pred = fmaxf(z, 0.f) * 20.f + 1.f;

#pragma unroll
  for (int off = 32; off > 0; off >>= 1) pred += __shfl_down(pred, off);
  if ((tid & 63) == 0) wsum[tid >> 6] = pred;
  __syncthreads();
  if (tid == 0) atomicAdd(&sums[b], wsum[0] + wsum[1] + wsum[2] + wsum[3]);
}

// ---------------- K2: finalize radii ----------------
__global__ void finalize_kernel(const float* __restrict__ sums,
                                int* __restrict__ rads) {
  int t = threadIdx.x;
  if (t < 16) {
    float mean = sums[t] * (1.f / (float)HW);
    float ksz = fminf(fmaxf(floorf(mean), 1.f), 21.f);
    rads[t] = (int)floorf((ksz - 1.f) * 0.5f);
  }
}

// ---------------- K3: MFMA Toeplitz depthwise conv ----------------
// One block per (b,c): full 128x128 image + halo staged as f16 in LDS.
// Wave w owns y-tiles {2w,2w+1} x all 8 x-tiles. Per dy: Toeplitz B in regs.
template <int CB, int CNT>
__device__ __forceinline__ void conv_chunk(const _Float16* xs, const _Float16* wm,
                                           f32x4 (&acc)[2][8], int lane, int ytbase) {
  const int n_l = lane & 15;        // B: n  /  A: m  (same lane expression)
  const int q = lane >> 4;
  const int kb = q * 8;             // k-group base

  // Toeplitz B fragments: B[k,n] = wm[ky][k-n] (mask already folded into wm)
  f16x8 Bf[CNT];
#pragma unroll
  for (int d = 0; d < CNT; ++d) {
    f16x8 v;
#pragma unroll
    for (int j = 0; j < 8; ++j) {
      int t = kb + j - n_l;
      int tc = t < 0 ? 0 : (t > 20 ? 20 : t);
      _Float16 w = wm[(CB + d) * WM_STRIDE + tc];
      v[j] = (t >= 0 && t <= 20) ? w : (_Float16)0.f;
    }
    Bf[d] = v;
  }
  // packed remainder: k-slot = 4*d8 + k2 covers input cols 32..35 of dy=CB+d8
  f16x8 B2f;
#pragma unroll
  for (int j = 0; j < 8; ++j) {
    int jj = kb + j;
    int d8 = jj >> 2, k2 = jj & 3;
    int dcl = d8 < CNT ? d8 : CNT - 1;
    int t = 32 + k2 - n_l;          // >= 17 always
    int tc = t > 20 ? 20 : t;
    _Float16 w = wm[(CB + dcl) * WM_STRIDE + tc];
    B2f[j] = (t <= 20 && d8 < CNT) ? w : (_Float16)0.f;
  }
  const int kya = CB + ((2 * q) < CNT ? 2 * q : CNT - 1);
  const int kyb = CB + ((2 * q + 1) < CNT ? 2 * q + 1 : CNT - 1);

#pragma unroll
  for (int tyi = 0; tyi < 2; ++tyi) {
    const int ty = ytbase + tyi;
#pragma unroll
    for (int tx = 0; tx < 8; ++tx) {
      f32x4 a = acc[tyi][tx];
      const _Float16* base = xs + (16 * ty + n_l) * XS_STRIDE + 16 * tx + kb;
#pragma unroll
      for (int d = 0; d < CNT; ++d) {
        f16x8 av = *(const f16x8*)(base + (CB + d) * XS_STRIDE);  // 16B-aligned
        a = __builtin_amdgcn_mfma_f32_16x16x32_f16(av, Bf[d], a, 0, 0, 0);
      }
      {
        const _Float16* pa = xs + (16 * ty + kya + n_l) * XS_STRIDE + 16 * tx + 32;
        const _Float16* pb = xs + (16 * ty + kyb + n_l) * XS_STRIDE + 16 * tx + 32;
        f16x4 lo = *(const f16x4*)pa;
        f16x4 hi = *(const f16x4*)pb;
        f16x8 av;
        av[0] = lo[0]; av[1] = lo[1]; av[2] = lo[2]; av[3] = lo[3];
        av[4] = hi[0]; av[5] = hi[1]; av[6] = hi[2]; av[7] = hi[3];
        a = __builtin_amdgcn_mfma_f32_16x16x32_f16(av, B2f, a, 0, 0, 0);
      }
      acc[tyi][tx] = a;
    }
  }
}

__global__ __launch_bounds__(256) void conv_kernel(
    const float* __restrict__ x, const float* __restrict__ gauss,
    const int* __restrict__ rads, float* __restrict__ out) {
  __shared__ _Float16 xs[148 * XS_STRIDE];
  __shared__ _Float16 wm[21 * WM_STRIDE];

  const int c = blockIdx.x, b = blockIdx.y;
  const int tid = threadIdx.x;
  const int r = rads[b];  // uniform
  const float* img = x + ((size_t)(b * CCH + c)) * HW;

  // stage reflect-padded image as f16
  for (int i = tid; i < 148 * 148; i += 256) {
    int row = i / 148, col = i - row * 148;
    int gy = row - 10; gy = gy < 0 ? -gy : (gy > 127 ? 254 - gy : gy);
    int gx = col - 10; gx = gx < 0 ? -gx : (gx > 127 ? 254 - gx : gx);
    xs[row * XS_STRIDE + col] = (_Float16)img[gy * 128 + gx];
  }
  // stage masked kernel as f16 (2D mask folded in); strided loop covers all 441
  for (int i = tid; i < 441; i += 256) {
    int ky = i / 21, kx = i - ky * 21;
    int ay = ky - 10; ay = ay < 0 ? -ay : ay;
    int ax = kx - 10; ax = ax < 0 ? -ax : ax;
    float wv = (ay <= r && ax <= r) ? gauss[(size_t)c * 441 + i] : 0.f;
    wm[ky * WM_STRIDE + kx] = (_Float16)wv;
  }
  __syncthreads();

  const int lane = tid & 63;
  const int ytbase = (tid >> 6) * 2;
  f32x4 acc[2][8];
#pragma unroll
  for (int i = 0; i < 2; ++i)
#pragma unroll
    for (int j = 0; j < 8; ++j) {
      f32x4 z = {0.f, 0.f, 0.f, 0.f};
      acc[i][j] = z;
    }

  conv_chunk<0, 8>(xs, wm, acc, lane, ytbase);
  conv_chunk<8, 8>(xs, wm, acc, lane, ytbase);
  conv_chunk<16, 5>(xs, wm, acc, lane, ytbase);

  // D: col = lane&15, row = 4*(lane>>4) + reg
  float* outc = out + ((size_t)(b * CCH + c)) * HW;
  const int row0 = (lane >> 4) * 4;
  const int coln = lane & 15;
#pragma unroll
  for (int tyi = 0; tyi < 2; ++tyi)
#pragma unroll
    for (int tx = 0; tx < 8; ++tx) {
      f32x4 a = acc[tyi][tx];
      float* po = outc + (16 * (ytbase + tyi) + row0) * 128 + 16 * tx + coln;
#pragma unroll
      for (int e = 0; e < 4; ++e) po[e * 128] = a[e];
    }
}

extern "C" void kernel_launch(void* const* d_in, const int* in_sizes, int n_in,
                              void* d_out, int out_size, void* d_ws, size_t ws_size,
                              hipStream_t stream) {
  const float* x     = (const float*)d_in[0];
  const float* gauss = (const float*)d_in[1];
  const float* w1    = (const float*)d_in[2];
  const float* b1    = (const float*)d_in[3];
  const float* w2    = (const float*)d_in[4];
  const float* b2    = (const float*)d_in[5];
  float* out = (float*)d_out;

  float* sums = (float*)d_ws;
  int* rads = (int*)((char*)d_ws + 64);

  (void)hipMemsetAsync(d_ws, 0, 64, stream);
  pred_kernel<<<dim3(64, 16), 256, 0, stream>>>(x, w1, b1, w2, b2, sums);
  finalize_kernel<<<1, 64, 0, stream>>>(sums, rads);
  conv_kernel<<<dim3(256, 16), 256, 0, stream>>>(x, gauss, rads, out);
}

// Round 8
// 646.231 us; speedup vs baseline: 2.0045x; 1.2355x over previous
//
#include <hip/hip_runtime.h>

#define HW 16384
#define CCH 256
#define XS_STRIDE 168   // 84 rows staged; bank step 20 mod 32 -> full quad sweep
#define WM_STRIDE 22
#define WT_STRIDE 264   // pred weight/x LDS stride (>=256, mult of 8)

typedef _Float16 f16x8 __attribute__((ext_vector_type(8)));
typedef _Float16 f16x4 __attribute__((ext_vector_type(4)));
typedef float f32x4 __attribute__((ext_vector_type(4)));

// ---------------- K1: predictor via MFMA ----------------
// grid (256, 16), block 256. Each block: 64 pixels of one batch.
// D[o][px] = w1(32x256) @ x(256x64-slice); then relu/w2 epilogue in regs.
__global__ __launch_bounds__(256) void pred_kernel(
    const float* __restrict__ x, const float* __restrict__ w1,
    const float* __restrict__ b1, const float* __restrict__ w2,
    const float* __restrict__ b2, float* __restrict__ sums) {
  __shared__ _Float16 wt[32 * WT_STRIDE];   // [o][c]
  __shared__ _Float16 xt[64 * WT_STRIDE];   // [px][c] (transposed tile)
  __shared__ float wsum[4];

  const int tid = threadIdx.x;
  const int b = blockIdx.y;
  const int pix0 = blockIdx.x * 64;
  const float* xb = x + (size_t)b * CCH * HW + pix0;

  // stage w1 -> f16 [o][c]
  for (int i = tid; i < 32 * 256; i += 256) {
    int o = i >> 8, c = i & 255;
    wt[o * WT_STRIDE + c] = (_Float16)w1[i];
  }
  // stage x tile transposed: read [c][px] coalesced float4, write [px][c]
  for (int it = 0; it < 16; ++it) {
    int flat = it * 1024 + tid * 4;       // 4096 floats per iter
    int c = flat >> 6, px = flat & 63;
    float4 v = *(const float4*)(xb + (size_t)c * HW + px);
    xt[(px + 0) * WT_STRIDE + c] = (_Float16)v.x;
    xt[(px + 1) * WT_STRIDE + c] = (_Float16)v.y;
    xt[(px + 2) * WT_STRIDE + c] = (_Float16)v.z;
    xt[(px + 3) * WT_STRIDE + c] = (_Float16)v.w;
  }
  __syncthreads();

  const int lane = tid & 63;
  const int w = tid >> 6;          // wave id -> 16-px group
  const int n_l = lane & 15;
  const int q = lane >> 4;

  f32x4 acc0 = {0.f, 0.f, 0.f, 0.f};
  f32x4 acc1 = {0.f, 0.f, 0.f, 0.f};
  const _Float16* wrow0 = wt + n_l * WT_STRIDE;          // A tile0: o = n_l
  const _Float16* wrow1 = wt + (16 + n_l) * WT_STRIDE;   // A tile1: o = 16+n_l
  const _Float16* xrow  = xt + (16 * w + n_l) * WT_STRIDE; // B: px = 16w+n_l

#pragma unroll
  for (int ck = 0; ck < 8; ++ck) {
    int co = ck * 32 + 8 * q;                 // k = 8q + j within chunk
    f16x8 Bv = *(const f16x8*)(xrow + co);
    f16x8 A0 = *(const f16x8*)(wrow0 + co);
    f16x8 A1 = *(const f16x8*)(wrow1 + co);
    acc0 = __builtin_amdgcn_mfma_f32_16x16x32_f16(A0, Bv, acc0, 0, 0, 0);
    acc1 = __builtin_amdgcn_mfma_f32_16x16x32_f16(A1, Bv, acc1, 0, 0, 0);
  }

  // epilogue: lane holds h[o] for o = 16*mt + 4q + e at px = n_l
  float zp = 0.f;
#pragma unroll
  for (int e = 0; e < 4; ++e) {
    int o0 = 4 * q + e, o1 = 16 + 4 * q + e;
    zp += fmaxf(acc0[e] + b1[o0], 0.f) * w2[o0];
    zp += fmaxf(acc1[e] + b1[o1], 0.f) * w2[o1];
  }
  zp += __shfl_xor(zp, 16);
  zp += __shfl_xor(zp, 32);                   // all 4 q-copies now full
  float pred = (fmaxf(zp + b2[0], 0.f) * 20.f + 1.f) * 0.25f;  // /4 copies
#pragma unroll
  for (int off = 32; off > 0; off >>= 1) pred += __shfl_down(pred, off);
  if (lane == 0) wsum[w] = pred;
  __syncthreads();
  if (tid == 0) atomicAdd(&sums[b], wsum[0] + wsum[1] + wsum[2] + wsum[3]);
}

// ---------------- K2: finalize radii ----------------
__global__ void finalize_kernel(const float* __restrict__ sums,
                                int* __restrict__ rads) {
  int t = threadIdx.x;
  if (t < 16) {
    float mean = sums[t] * (1.f / (float)HW);
    float ksz = fminf(fmaxf(floorf(mean), 1.f), 21.f);
    rads[t] = (int)floorf((ksz - 1.f) * 0.5f);
  }
}

// ---------------- K3: MFMA Toeplitz depthwise conv ----------------
// grid (2, 256, 16): half-image (64 out rows) per block; 84x148 halo in LDS.
// Wave w owns out rows [y0+16w, y0+16w+16), all 8 x-tiles.
template <int CB, int CNT>
__device__ __forceinline__ void conv_chunk(const _Float16* xs, const _Float16* wm,
                                           f32x4 (&acc)[8], int lane, int wrow) {
  const int n_l = lane & 15;        // B: n  /  A: m  (same lane bits)
  const int q = lane >> 4;
  const int kb = q * 8;             // k-group base

  // Toeplitz B fragments: B[k,n] = wm[ky][k-n] (mask folded into wm)
  f16x8 Bf[CNT];
#pragma unroll
  for (int d = 0; d < CNT; ++d) {
    f16x8 v;
#pragma unroll
    for (int j = 0; j < 8; ++j) {
      int t = kb + j - n_l;
      int tc = t < 0 ? 0 : (t > 20 ? 20 : t);
      _Float16 wv = wm[(CB + d) * WM_STRIDE + tc];
      v[j] = (t >= 0 && t <= 20) ? wv : (_Float16)0.f;
    }
    Bf[d] = v;
  }
  // packed remainder: k-slot jj=4*d8+k2 covers input cols 32..35 of dy=CB+d8
  f16x8 B2f;
#pragma unroll
  for (int j = 0; j < 8; ++j) {
    int jj = kb + j;
    int d8 = jj >> 2, k2 = jj & 3;
    int dcl = d8 < CNT ? d8 : CNT - 1;
    int t = 32 + k2 - n_l;          // >= 17 always
    int tc = t > 20 ? 20 : t;
    _Float16 wv = wm[(CB + dcl) * WM_STRIDE + tc];
    B2f[j] = (t <= 20 && d8 < CNT) ? wv : (_Float16)0.f;
  }
  const int kya = CB + ((2 * q) < CNT ? 2 * q : CNT - 1);
  const int kyb = CB + ((2 * q + 1) < CNT ? 2 * q + 1 : CNT - 1);

#pragma unroll
  for (int tx = 0; tx < 8; ++tx) {
    f32x4 a = acc[tx];
    const _Float16* base = xs + (wrow + n_l) * XS_STRIDE + 16 * tx + kb;
#pragma unroll
    for (int d = 0; d < CNT; ++d) {
      f16x8 av = *(const f16x8*)(base + (CB + d) * XS_STRIDE);  // 16B-aligned
      a = __builtin_amdgcn_mfma_f32_16x16x32_f16(av, Bf[d], a, 0, 0, 0);
    }
    {
      const _Float16* pa = xs + (wrow + kya + n_l) * XS_STRIDE + 16 * tx + 32;
      const _Float16* pb = xs + (wrow + kyb + n_l) * XS_STRIDE + 16 * tx + 32;
      f16x4 lo = *(const f16x4*)pa;
      f16x4 hi = *(const f16x4*)pb;
      f16x8 av;
      av[0] = lo[0]; av[1] = lo[1]; av[2] = lo[2]; av[3] = lo[3];
      av[4] = hi[0]; av[5] = hi[1]; av[6] = hi[2]; av[7] = hi[3];
      a = __builtin_amdgcn_mfma_f32_16x16x32_f16(av, B2f, a, 0, 0, 0);
    }
    acc[tx] = a;
  }
}

__global__ __launch_bounds__(256) void conv_kernel(
    const float* __restrict__ x, const float* __restrict__ gauss,
    const int* __restrict__ rads, float* __restrict__ out) {
  __shared__ _Float16 xs[84 * XS_STRIDE];   // 28.2 KB -> 5 blocks/CU
  __shared__ _Float16 wm[21 * WM_STRIDE];

  const int half = blockIdx.x;              // 0/1: which 64-row half
  const int c = blockIdx.y, b = blockIdx.z;
  const int y0 = half * 64;
  const int tid = threadIdx.x;
  const int r = rads[b];  // uniform
  const float* img = x + ((size_t)(b * CCH + c)) * HW;

  // stage reflect-padded half-image as f16: xs row 0 = image row y0-10
  for (int i = tid; i < 84 * 148; i += 256) {
    int row = i / 148, col = i - row * 148;
    int gy = y0 + row - 10; gy = gy < 0 ? -gy : (gy > 127 ? 254 - gy : gy);
    int gx = col - 10;      gx = gx < 0 ? -gx : (gx > 127 ? 254 - gx : gx);
    xs[row * XS_STRIDE + col] = (_Float16)img[gy * 128 + gx];
  }
  // stage masked kernel as f16 (2D mask folded in)
  for (int i = tid; i < 441; i += 256) {
    int ky = i / 21, kx = i - ky * 21;
    int ay = ky - 10; ay = ay < 0 ? -ay : ay;
    int ax = kx - 10; ax = ax < 0 ? -ax : ax;
    float wv = (ay <= r && ax <= r) ? gauss[(size_t)c * 441 + i] : 0.f;
    wm[ky * WM_STRIDE + kx] = (_Float16)wv;
  }
  __syncthreads();

  const int lane = tid & 63;
  const int w = tid >> 6;
  const int wrow = 16 * w;                  // local out-row base of this wave
  f32x4 acc[8];
#pragma unroll
  for (int j = 0; j < 8; ++j) {
    f32x4 z = {0.f, 0.f, 0.f, 0.f};
    acc[j] = z;
  }

  conv_chunk<0, 8>(xs, wm, acc, lane, wrow);
  conv_chunk<8, 8>(xs, wm, acc, lane, wrow);
  conv_chunk<16, 5>(xs, wm, acc, lane, wrow);

  // D: col = lane&15, row = 4*(lane>>4) + reg
  float* outc = out + ((size_t)(b * CCH + c)) * HW;
  const int row0 = (lane >> 4) * 4;
  const int coln = lane & 15;
#pragma unroll
  for (int tx = 0; tx < 8; ++tx) {
    f32x4 a = acc[tx];
    float* po = outc + (size_t)(y0 + wrow + row0) * 128 + 16 * tx + coln;
#pragma unroll
    for (int e = 0; e < 4; ++e) po[e * 128] = a[e];
  }
}

extern "C" void kernel_launch(void* const* d_in, const int* in_sizes, int n_in,
                              void* d_out, int out_size, void* d_ws, size_t ws_size,
                              hipStream_t stream) {
  const float* x     = (const float*)d_in[0];
  const float* gauss = (const float*)d_in[1];
  const float* w1    = (const float*)d_in[2];
  const float* b1    = (const float*)d_in[3];
  const float* w2    = (const float*)d_in[4];
  const float* b2    = (const float*)d_in[5];
  float* out = (float*)d_out;

  float* sums = (float*)d_ws;
  int* rads = (int*)((char*)d_ws + 64);

  (void)hipMemsetAsync(d_ws, 0, 64, stream);
  pred_kernel<<<dim3(256, 16), 256, 0, stream>>>(x, w1, b1, w2, b2, sums);
  finalize_kernel<<<1, 64, 0, stream>>>(sums, rads);
  conv_kernel<<<dim3(2, 256, 16), 256, 0, stream>>>(x, gauss, rads, out);
}

// Round 10
// 631.456 us; speedup vs baseline: 2.0514x; 1.0234x over previous
//
#include <hip/hip_runtime.h>

#define HW 16384
#define CCH 256
#define XS_STRIDE 192   // multiple of 64: col-XOR swizzle stays in-row (bijective)
#define WM_STRIDE 22
#define WT_STRIDE 264   // pred w1 LDS stride (f16), mult of 8
#define PS 258          // pred x-chunk row stride (f16)

typedef _Float16 f16x8 __attribute__((ext_vector_type(8)));
typedef _Float16 f16x4 __attribute__((ext_vector_type(4)));
typedef _Float16 f16x2 __attribute__((ext_vector_type(2)));
typedef float f32x4 __attribute__((ext_vector_type(4)));

// ---------------- K1: predictor via MFMA, chunked [c][px] staging ----------------
// grid (64, 16), block 256. Block = 256 px of one batch; K-loop over 8 chunks of 32 c.
__global__ __launch_bounds__(256) void pred_kernel(
    const float* __restrict__ x, const float* __restrict__ w1,
    const float* __restrict__ b1, const float* __restrict__ w2,
    const float* __restrict__ b2, float* __restrict__ sums) {
  __shared__ _Float16 wt[32 * WT_STRIDE];  // [o][c]
  __shared__ _Float16 xc[32 * PS];         // [c_local][px] current chunk
  __shared__ float wsum[4];

  const int tid = threadIdx.x;
  const int b = blockIdx.y;
  const int px0 = blockIdx.x * 256;
  const float* xb = x + (size_t)b * CCH * HW + px0;

  for (int i = tid; i < 32 * 256; i += 256)
    wt[(i >> 8) * WT_STRIDE + (i & 255)] = (_Float16)w1[i];

  const int lane = tid & 63;
  const int w = tid >> 6;
  const int n_l = lane & 15;
  const int q = lane >> 4;

  f32x4 acc0[4], acc1[4];
#pragma unroll
  for (int i = 0; i < 4; ++i) {
    f32x4 z = {0.f, 0.f, 0.f, 0.f};
    acc0[i] = z; acc1[i] = z;
  }

  for (int ck = 0; ck < 8; ++ck) {
    __syncthreads();  // xc reuse guard (and wt-ready before first MFMA)
#pragma unroll
    for (int it = 0; it < 8; ++it) {
      int flat = it * 1024 + tid * 4;
      int cl = flat >> 8, px = flat & 255;
      float4 v = *(const float4*)(xb + (size_t)(32 * ck + cl) * HW + px);
      f16x2 p0 = {(_Float16)v.x, (_Float16)v.y};
      f16x2 p1 = {(_Float16)v.z, (_Float16)v.w};
      *(f16x2*)(&xc[cl * PS + px]) = p0;
      *(f16x2*)(&xc[cl * PS + px + 2]) = p1;
    }
    __syncthreads();

    f16x8 A0 = *(const f16x8*)(wt + n_l * WT_STRIDE + 32 * ck + 8 * q);
    f16x8 A1 = *(const f16x8*)(wt + (16 + n_l) * WT_STRIDE + 32 * ck + 8 * q);
#pragma unroll
    for (int i = 0; i < 4; ++i) {
      int pxb = 16 * (4 * i + w) + n_l;
      f16x8 Bv;
#pragma unroll
      for (int j = 0; j < 8; ++j) Bv[j] = xc[(8 * q + j) * PS + pxb];
      acc0[i] = __builtin_amdgcn_mfma_f32_16x16x32_f16(A0, Bv, acc0[i], 0, 0, 0);
      acc1[i] = __builtin_amdgcn_mfma_f32_16x16x32_f16(A1, Bv, acc1[i], 0, 0, 0);
    }
  }

  // epilogue: lane holds h[o=4q+e] (and 16+4q+e) at px = 16*(4i+w)+n_l
  float psum = 0.f;
#pragma unroll
  for (int i = 0; i < 4; ++i) {
    float zp = 0.f;
#pragma unroll
    for (int e = 0; e < 4; ++e) {
      int o0 = 4 * q + e, o1 = 16 + 4 * q + e;
      zp += fmaxf(acc0[i][e] + b1[o0], 0.f) * w2[o0];
      zp += fmaxf(acc1[i][e] + b1[o1], 0.f) * w2[o1];
    }
    zp += __shfl_xor(zp, 16);
    zp += __shfl_xor(zp, 32);                 // full o-sum, q-duplicated x4
    psum += fmaxf(zp + b2[0], 0.f) * 20.f + 1.f;
  }
#pragma unroll
  for (int off = 32; off > 0; off >>= 1) psum += __shfl_down(psum, off);
  if (lane == 0) wsum[w] = psum * 0.25f;      // /4 q-copies
  __syncthreads();
  if (tid == 0) atomicAdd(&sums[b], wsum[0] + wsum[1] + wsum[2] + wsum[3]);
}

// ---------------- K2: MFMA Toeplitz depthwise conv (finalize folded in) ----------------
// grid (2, 256, 16): 64-out-row half per block; 84x148 halo in LDS.
// Swizzle: col-local XOR within the row (stride 192 = mult of 64 -> bijective;
// all vector accesses are 16B groups at col%8==0 = one swizzle unit).
#define SWZ(row, col) ((row) * XS_STRIDE + ((col) ^ (((row) & 7) << 3)))

template <int CB, int CNT>
__device__ __forceinline__ void conv_chunk(const _Float16* xs, const _Float16* wm,
                                           f32x4 (&acc)[8], int lane, int wrow) {
  const int n_l = lane & 15;        // B: n  /  A: m  (same lane bits)
  const int q = lane >> 4;
  const int kb = q * 8;             // k-group base

  // Toeplitz B fragments: B[k,n] = wm[ky][k-n] (mask folded into wm)
  f16x8 Bf[CNT];
#pragma unroll
  for (int d = 0; d < CNT; ++d) {
    f16x8 v;
#pragma unroll
    for (int j = 0; j < 8; ++j) {
      int t = kb + j - n_l;
      int tc = t < 0 ? 0 : (t > 20 ? 20 : t);
      _Float16 wv = wm[(CB + d) * WM_STRIDE + tc];
      v[j] = (t >= 0 && t <= 20) ? wv : (_Float16)0.f;
    }
    Bf[d] = v;
  }
  // packed remainder: k-slot jj=4*d8+k2 covers input cols 32..35 of dy=CB+d8
  f16x8 B2f;
#pragma unroll
  for (int j = 0; j < 8; ++j) {
    int jj = kb + j;
    int d8 = jj >> 2, k2 = jj & 3;
    int dcl = d8 < CNT ? d8 : CNT - 1;
    int t = 32 + k2 - n_l;          // >= 17 always
    int tc = t > 20 ? 20 : t;
    _Float16 wv = wm[(CB + dcl) * WM_STRIDE + tc];
    B2f[j] = (t <= 20 && d8 < CNT) ? wv : (_Float16)0.f;
  }
  const int kya = CB + ((2 * q) < CNT ? 2 * q : CNT - 1);
  const int kyb = CB + ((2 * q + 1) < CNT ? 2 * q + 1 : CNT - 1);

#pragma unroll
  for (int tx = 0; tx < 8; ++tx) {
    f32x4 a = acc[tx];
#pragma unroll
    for (int d = 0; d < CNT; ++d) {
      int row = wrow + n_l + CB + d;
      f16x8 av = *(const f16x8*)(xs + SWZ(row, 16 * tx + kb));  // one 16B swz unit
      a = __builtin_amdgcn_mfma_f32_16x16x32_f16(av, Bf[d], a, 0, 0, 0);
    }
    {
      int ra = wrow + kya + n_l, rb = wrow + kyb + n_l;
      f16x4 lo = *(const f16x4*)(xs + SWZ(ra, 16 * tx + 32));
      f16x4 hi = *(const f16x4*)(xs + SWZ(rb, 16 * tx + 32));
      f16x8 av;
      av[0] = lo[0]; av[1] = lo[1]; av[2] = lo[2]; av[3] = lo[3];
      av[4] = hi[0]; av[5] = hi[1]; av[6] = hi[2]; av[7] = hi[3];
      a = __builtin_amdgcn_mfma_f32_16x16x32_f16(av, B2f, a, 0, 0, 0);
    }
    acc[tx] = a;
  }
}

__global__ __launch_bounds__(256, 4) void conv_kernel(
    const float* __restrict__ x, const float* __restrict__ gauss,
    const float* __restrict__ sums, float* __restrict__ out) {
  __shared__ _Float16 xs[84 * XS_STRIDE];   // 32.25 KB -> 4 blocks/CU
  __shared__ _Float16 wm[21 * WM_STRIDE];

  const int half = blockIdx.x;              // 0/1: which 64-row half
  const int c = blockIdx.y, b = blockIdx.z;
  const int y0 = half * 64;
  const int tid = threadIdx.x;

  // finalize folded in (uniform scalar math)
  float mean = sums[b] * (1.f / (float)HW);
  float ksz = fminf(fmaxf(floorf(mean), 1.f), 21.f);
  const int r = (int)floorf((ksz - 1.f) * 0.5f);

  const float* img = x + ((size_t)(b * CCH + c)) * HW;

  // stage reflect-padded half-image as f16, 8 cols/thread, vector LDS writes.
  // 19 groups of 8 cover cols 0..151 (148..151 = junk in pad, never read).
  for (int g = tid; g < 84 * 19; g += 256) {
    int row = g / 19, cg = (g - row * 19) * 8;
    int gy = y0 + row - 10; gy = gy < 0 ? -gy : (gy > 127 ? 254 - gy : gy);
    const float* grow = img + gy * 128;
    f16x8 v;
#pragma unroll
    for (int e = 0; e < 8; ++e) {
      int gx = cg + e - 10; gx = gx < 0 ? -gx : (gx > 127 ? 254 - gx : gx);
      v[e] = (_Float16)grow[gx];
    }
    *(f16x8*)(&xs[SWZ(row, cg)]) = v;
  }
  // stage masked kernel as f16 (2D mask folded in)
  for (int i = tid; i < 441; i += 256) {
    int ky = i / 21, kx = i - ky * 21;
    int ay = ky - 10; ay = ay < 0 ? -ay : ay;
    int ax = kx - 10; ax = ax < 0 ? -ax : ax;
    float wv = (ay <= r && ax <= r) ? gauss[(size_t)c * 441 + i] : 0.f;
    wm[ky * WM_STRIDE + kx] = (_Float16)wv;
  }
  __syncthreads();

  const int lane = tid & 63;
  const int w = tid >> 6;
  const int wrow = 16 * w;                  // local out-row base of this wave
  f32x4 acc[8];
#pragma unroll
  for (int j = 0; j < 8; ++j) {
    f32x4 z = {0.f, 0.f, 0.f, 0.f};
    acc[j] = z;
  }

  conv_chunk<0, 8>(xs, wm, acc, lane, wrow);
  conv_chunk<8, 8>(xs, wm, acc, lane, wrow);
  conv_chunk<16, 5>(xs, wm, acc, lane, wrow);

  // D: col = lane&15, row = 4*(lane>>4) + reg
  float* outc = out + ((size_t)(b * CCH + c)) * HW;
  const int row0 = (lane >> 4) * 4;
  const int coln = lane & 15;
#pragma unroll
  for (int tx = 0; tx < 8; ++tx) {
    f32x4 a = acc[tx];
    float* po = outc + (size_t)(y0 + wrow + row0) * 128 + 16 * tx + coln;
#pragma unroll
    for (int e = 0; e < 4; ++e) po[e * 128] = a[e];
  }
}

extern "C" void kernel_launch(void* const* d_in, const int* in_sizes, int n_in,
                              void* d_out, int out_size, void* d_ws, size_t ws_size,
                              hipStream_t stream) {
  const float* x     = (const float*)d_in[0];
  const float* gauss = (const float*)d_in[1];
  const float* w1    = (const float*)d_in[2];
  const float* b1    = (const float*)d_in[3];
  const float* w2    = (const float*)d_in[4];
  const float* b2    = (const float*)d_in[5];
  float* out = (float*)d_out;

  float* sums = (float*)d_ws;

  (void)hipMemsetAsync(d_ws, 0, 64, stream);
  pred_kernel<<<dim3(64, 16), 256, 0, stream>>>(x, w1, b1, w2, b2, sums);
  conv_kernel<<<dim3(2, 256, 16), 256, 0, stream>>>(x, gauss, sums, out);
}